// Round 8
// baseline (686.798 us; speedup 1.0000x reference)
//
#include <hip/hip_runtime.h>
#include <hip/hip_bf16.h>

#ifndef D_FEAT
#define D_FEAT 128
#endif

typedef __attribute__((ext_vector_type(8))) short bf16x8;
typedef __attribute__((ext_vector_type(4))) float f32x4;
typedef unsigned long long u64;

#define GP 136   // LDS agg row stride in shorts (=68 words; balanced b128 banks)

// ---------------- bf16 helpers (RN-even) ----------------
__device__ __forceinline__ unsigned short f2bf(float f) {
    union { float f; unsigned u; } v; v.f = f;
    unsigned r = v.u + 0x7FFF + ((v.u >> 16) & 1);
    return (unsigned short)(r >> 16);
}
__device__ __forceinline__ float bf2f_lo(unsigned u) {
    union { unsigned u; float f; } v; v.u = u << 16; return v.f;
}
__device__ __forceinline__ float bf2f_hi(unsigned u) {
    union { unsigned u; float f; } v; v.u = u & 0xFFFF0000u; return v.f;
}
__device__ __forceinline__ float bfu(unsigned short s) {
    union { unsigned u; float f; } v; v.u = ((unsigned)s) << 16; return v.f;
}

// ---------------------------------------------------------------------------
// Scan kernels for per-node CSR offsets.
// ---------------------------------------------------------------------------
__global__ void scan_block_sums(const int* __restrict__ counts, int* __restrict__ bsum, int N) {
    __shared__ int red[256];
    const int b = blockIdx.x, t = threadIdx.x;
    const int base = b * 1024 + t * 4;
    int s = 0;
#pragma unroll
    for (int j = 0; j < 4; ++j) { int i = base + j; if (i < N) s += counts[i]; }
    red[t] = s; __syncthreads();
    for (int off = 128; off > 0; off >>= 1) {
        if (t < off) red[t] += red[t + off];
        __syncthreads();
    }
    if (t == 0) bsum[b] = red[0];
}

__global__ void scan_offsets(int* __restrict__ bsum, int nb, int* __restrict__ row_ptr, int N) {
    __shared__ int sh[128];
    const int t = threadIdx.x;
    const int v = (t < nb) ? bsum[t] : 0;
    sh[t] = v; __syncthreads();
    for (int off = 1; off < 128; off <<= 1) {
        int add = (t >= off) ? sh[t - off] : 0;
        __syncthreads();
        sh[t] += add;
        __syncthreads();
    }
    const int incl = sh[t];
    if (t < nb) bsum[t] = incl - v;
    if (t == nb - 1) row_ptr[N] = incl;
}

__global__ void scan_final(const int* __restrict__ counts, const int* __restrict__ bsum,
                           int* __restrict__ row_ptr, int* __restrict__ pos, int N) {
    __shared__ int tsum[256];
    const int b = blockIdx.x, t = threadIdx.x;
    const int base = b * 1024 + t * 4;
    int c[4]; int s = 0;
#pragma unroll
    for (int j = 0; j < 4; ++j) { int i = base + j; c[j] = (i < N) ? counts[i] : 0; s += c[j]; }
    tsum[t] = s; __syncthreads();
    const int v = s;
    for (int off = 1; off < 256; off <<= 1) {
        int add = (t >= off) ? tsum[t - off] : 0;
        __syncthreads();
        tsum[t] += add;
        __syncthreads();
    }
    int excl = tsum[t] - v + bsum[b];
#pragma unroll
    for (int j = 0; j < 4; ++j) {
        int i = base + j;
        if (i < N) { row_ptr[i] = excl; pos[i] = excl; excl += c[j]; }
    }
}

// ---------------------------------------------------------------------------
// 8-way dst-range partition split + per-node histogram (fused: one dst pass).
// Record: src | dst<<20 | bf16(w)<<40  (N < 2^20).
// ---------------------------------------------------------------------------
#define CHUNK 2048

__global__ void part_count(const int* __restrict__ dst, int E, int Q,
                           int* __restrict__ pcnt, int* __restrict__ counts) {
    __shared__ int c[8];
    const int t = threadIdx.x;
    if (t < 8) c[t] = 0;
    __syncthreads();
    const int base = blockIdx.x * CHUNK;
    const int lim = min(base + CHUNK, E);
    for (int i = base + t; i < lim; i += 256) {
        const int d = dst[i];
        atomicAdd(&c[d / Q], 1);
        atomicAdd(&counts[d], 1);
    }
    __syncthreads();
    if (t < 8) pcnt[blockIdx.x * 8 + t] = c[t];
}

// 8 waves; wave w scans partition w's per-chunk counts -> per-chunk offsets.
__global__ void part_scan(const int* __restrict__ pcnt, int nblk,
                          const int* __restrict__ row_ptr, int N, int Q,
                          int* __restrict__ poff) {
    const int wave = threadIdx.x >> 6;
    const int lane = threadIdx.x & 63;
    if (wave >= 8) return;
    int carry = row_ptr[min(wave * Q, N)];
    for (int i0 = 0; i0 < nblk; i0 += 64) {
        const int i = i0 + lane;
        const int v = (i < nblk) ? pcnt[i * 8 + wave] : 0;
        int s = v;
        for (int off = 1; off < 64; off <<= 1) {
            int tsh = __shfl_up(s, off);
            if (lane >= off) s += tsh;
        }
        if (i < nblk) poff[i * 8 + wave] = carry + (s - v);
        carry += __shfl(s, 63);
    }
}

__global__ void part_write(const int* __restrict__ src, const int* __restrict__ dst,
                           const float* __restrict__ ew, const int* __restrict__ poff,
                           u64* __restrict__ stg, int E, int Q) {
    __shared__ int cur[8];
    const int t = threadIdx.x;
    if (t < 8) cur[t] = poff[blockIdx.x * 8 + t];
    __syncthreads();
    const int base = blockIdx.x * CHUNK;
    const int lim = min(base + CHUNK, E);
    for (int i = base + t; i < lim; i += 256) {
        const int d = dst[i];
        const int p = atomicAdd(&cur[d / Q], 1);
        const u64 rec = (u64)(unsigned)src[i] | ((u64)(unsigned)d << 20)
                      | ((u64)f2bf(ew[i]) << 40);
        stg[p] = rec;
    }
}

// Blocks pinned to partition via bid&7: scattered writes confined to the
// partition's ~1.6MB region -> L2-resident.
__global__ void part_scatter(const u64* __restrict__ stg,
                             const int* __restrict__ row_ptr, int N, int Q,
                             int* __restrict__ pos, u64* __restrict__ erec) {
    const int p = blockIdx.x & 7;
    const int sub = blockIdx.x >> 3;
    const int nsub = gridDim.x >> 3;
    const int beg = row_ptr[min(p * Q, N)];
    const int end = row_ptr[min((p + 1) * Q, N)];
    for (int i = beg + sub * 256 + threadIdx.x; i < end; i += nsub * 256) {
        const u64 rec = stg[i];
        const int d = (int)((rec >> 20) & 0xFFFFF);
        const int fp = atomicAdd(&pos[d], 1);
        erec[fp] = rec;
    }
}

// ---------------------------------------------------------------------------
// x fp32 -> bf16 XH0 [N][128]
// ---------------------------------------------------------------------------
__global__ void convert_x(const float* __restrict__ x,
                          unsigned short* __restrict__ XH, int N) {
    int i = blockIdx.x * blockDim.x + threadIdx.x;
    if (i >= N * 32) return;
    float4 v = reinterpret_cast<const float4*>(x)[i];
    unsigned lo = (unsigned)f2bf(v.x) | ((unsigned)f2bf(v.y) << 16);
    unsigned hi = (unsigned)f2bf(v.z) | ((unsigned)f2bf(v.w) << 16);
    reinterpret_cast<uint2*>(XH)[i] = make_uint2(lo, hi);
}

// ---------------------------------------------------------------------------
// Pack W = [Wr;Ws] (256x128 fp32) into canonical B-fragment order, bf16:
// Wp[((ks*8 + ct)*64 + lane)*8 + j] = W[ks*32 + (lane>>4)*8 + j][ct*16 + (lane&15)]
// ---------------------------------------------------------------------------
__global__ void pack_W(const float* __restrict__ Wr, const float* __restrict__ Ws,
                       unsigned short* __restrict__ Wp) {
    int t = blockIdx.x * blockDim.x + threadIdx.x;   // 0..4095
    if (t >= 4096) return;
    const int lane = t & 63;
    const int ct = (t >> 6) & 7;
    const int ks = t >> 9;
    const int col = ct * 16 + (lane & 15);
    const int kbase = ks * 32 + (lane >> 4) * 8;
    unsigned short v[8];
#pragma unroll
    for (int j = 0; j < 8; ++j) {
        const int k = kbase + j;
        const float w = (k < 128) ? Wr[(size_t)k * 128 + col]
                                  : Ws[(size_t)(k - 128) * 128 + col];
        v[j] = f2bf(w);
    }
    *reinterpret_cast<uint4*>(Wp + (size_t)t * 8) = *reinterpret_cast<uint4*>(v);
}

// ---------------------------------------------------------------------------
// Fused layer: block = 128 nodes.
// Phase 1 (gather): wave w aggregates nodes [blk*128+w*32, +32) into LDS bf16.
// Phase 2 (GEMM): out = relu([agg | xh] @ [Wr;Ws] + br); agg from LDS,
// xh direct from global; 2x8 fragments of mfma 16x16x32 per wave.
// TO_BF16: write bf16 h -> XHo (layer 0); else fp32 -> out (layer 1).
// ---------------------------------------------------------------------------
template <bool WEIGHTED, bool TO_BF16>
__global__ void __launch_bounds__(256)
fused_layer(const unsigned short* __restrict__ XH,   // bf16 [N][128]
            const int* __restrict__ row_ptr,
            const u64* __restrict__ erec,
            const unsigned short* __restrict__ Wp,
            const float* __restrict__ br,
            unsigned short* __restrict__ XHo,
            float* __restrict__ out,
            int N) {
    __shared__ unsigned short sAgg[128][GP];

    const int tid = threadIdx.x;
    const int wave = tid >> 6;
    const int lane = tid & 63;
    const int r0 = blockIdx.x * 128;

    // ---- Phase 1: gather-aggregate into LDS ----
    for (int li = 0; li < 32; ++li) {
        const int node = r0 + wave * 32 + li;
        if (node >= N) break;
        const int beg = row_ptr[node];
        const int end = row_ptr[node + 1];
        float ax = 0.f, ay = 0.f;
        int i = beg;
        for (; i + 4 <= end; i += 4) {
            const u64 ra = erec[i], rb = erec[i + 1], rc = erec[i + 2], rd = erec[i + 3];
            const unsigned ua = *reinterpret_cast<const unsigned*>(XH + (size_t)(ra & 0xFFFFF) * 128 + lane * 2);
            const unsigned ub = *reinterpret_cast<const unsigned*>(XH + (size_t)(rb & 0xFFFFF) * 128 + lane * 2);
            const unsigned uc = *reinterpret_cast<const unsigned*>(XH + (size_t)(rc & 0xFFFFF) * 128 + lane * 2);
            const unsigned ud = *reinterpret_cast<const unsigned*>(XH + (size_t)(rd & 0xFFFFF) * 128 + lane * 2);
            const float wa = WEIGHTED ? bfu((unsigned short)(ra >> 40)) : 1.f;
            const float wb = WEIGHTED ? bfu((unsigned short)(rb >> 40)) : 1.f;
            const float wc = WEIGHTED ? bfu((unsigned short)(rc >> 40)) : 1.f;
            const float wd = WEIGHTED ? bfu((unsigned short)(rd >> 40)) : 1.f;
            ax += wa * bf2f_lo(ua) + wb * bf2f_lo(ub) + wc * bf2f_lo(uc) + wd * bf2f_lo(ud);
            ay += wa * bf2f_hi(ua) + wb * bf2f_hi(ub) + wc * bf2f_hi(uc) + wd * bf2f_hi(ud);
        }
        for (; i < end; ++i) {
            const u64 rr = erec[i];
            const unsigned u0 = *reinterpret_cast<const unsigned*>(XH + (size_t)(rr & 0xFFFFF) * 128 + lane * 2);
            const float w0 = WEIGHTED ? bfu((unsigned short)(rr >> 40)) : 1.f;
            ax += w0 * bf2f_lo(u0);
            ay += w0 * bf2f_hi(u0);
        }
        const unsigned o = (unsigned)f2bf(ax) | ((unsigned)f2bf(ay) << 16);
        *reinterpret_cast<unsigned*>(&sAgg[wave * 32 + li][lane * 2]) = o;
    }
    __syncthreads();

    // ---- Phase 2: MFMA GEMM ----
    const int wr0 = r0 + wave * 32;
    const int lk = (lane >> 4) * 8;

    int ra = wr0 + (lane & 15);
    int rb = ra + 16;
    if (ra >= N) ra = N - 1;   // clamped global loads; stores guarded below
    if (rb >= N) rb = N - 1;
    const unsigned short* pxa = XH + (size_t)ra * 128 + lk;
    const unsigned short* pxb = XH + (size_t)rb * 128 + lk;
    const unsigned short* pla = &sAgg[wave * 32 + (lane & 15)][lk];
    const unsigned short* plb = pla + 16 * GP;
    const unsigned short* pw = Wp + (size_t)lane * 8;

    f32x4 acc[2][8];
#pragma unroll
    for (int rt = 0; rt < 2; ++rt)
#pragma unroll
        for (int ct = 0; ct < 8; ++ct)
            acc[rt][ct] = (f32x4){0.f, 0.f, 0.f, 0.f};

#pragma unroll
    for (int ks = 0; ks < 8; ++ks) {
        // K 0..127 = agg (LDS), K 128..255 = x/h (global)
        const bf16x8 a0 = (ks < 4)
            ? *reinterpret_cast<const bf16x8*>(pla + ks * 32)
            : *reinterpret_cast<const bf16x8*>(pxa + (ks - 4) * 32);
        const bf16x8 a1 = (ks < 4)
            ? *reinterpret_cast<const bf16x8*>(plb + ks * 32)
            : *reinterpret_cast<const bf16x8*>(pxb + (ks - 4) * 32);
#pragma unroll
        for (int ct = 0; ct < 8; ++ct) {
            const bf16x8 b = *reinterpret_cast<const bf16x8*>(pw + (((ks << 3) + ct) << 9));
            acc[0][ct] = __builtin_amdgcn_mfma_f32_16x16x32_bf16(a0, b, acc[0][ct], 0, 0, 0);
            acc[1][ct] = __builtin_amdgcn_mfma_f32_16x16x32_bf16(a1, b, acc[1][ct], 0, 0, 0);
        }
    }

    // Epilogue. C/D: col = lane&15, row = (lane>>4)*4 + reg (within 16x16).
    const int crow = (lane >> 4) * 4;
    const int ccol = lane & 15;
#pragma unroll
    for (int ct = 0; ct < 8; ++ct) {
        const int col = ct * 16 + ccol;
        const float bias = br[col];
#pragma unroll
        for (int rt = 0; rt < 2; ++rt) {
#pragma unroll
            for (int reg = 0; reg < 4; ++reg) {
                const int row = wr0 + rt * 16 + crow + reg;
                if (row >= N) continue;
                const float v = fmaxf(acc[rt][ct][reg] + bias, 0.f);
                if (TO_BF16) {
                    XHo[(size_t)row * 128 + col] = f2bf(v);
                } else {
                    out[(size_t)row * 128 + col] = v;
                }
            }
        }
    }
}

extern "C" void kernel_launch(void* const* d_in, const int* in_sizes, int n_in,
                              void* d_out, int out_size, void* d_ws, size_t ws_size,
                              hipStream_t stream) {
    const float* x  = (const float*)d_in[0];
    const int*   ei = (const int*)d_in[1];     // [2, E] int32 (JAX x64 disabled)
    const float* ew = (const float*)d_in[2];
    const float* Wr0 = (const float*)d_in[3];
    const float* br0 = (const float*)d_in[4];
    const float* Ws0 = (const float*)d_in[5];
    const float* Wr1 = (const float*)d_in[6];
    const float* br1 = (const float*)d_in[7];
    const float* Ws1 = (const float*)d_in[8];

    const int N = in_sizes[0] / D_FEAT;
    const int E = in_sizes[1] / 2;
    const int* src = ei;
    const int* dst = ei + E;
    const int Q = (N + 7) / 8;          // dst-partition width

    // ---- workspace carve-up (16B aligned), ~80 MB ----
    char* w = (char*)d_ws;
    auto carve = [&](size_t bytes) { char* p = w; w += (bytes + 15) & ~(size_t)15; return p; };
    unsigned short* XH0 = (unsigned short*)carve((size_t)N * 128 * 2);  // 25.6 MB
    unsigned short* XH1 = (unsigned short*)carve((size_t)N * 128 * 2);  // 25.6 MB
    unsigned short* Wp0 = (unsigned short*)carve(256 * 128 * 2);
    unsigned short* Wp1 = (unsigned short*)carve(256 * 128 * 2);
    int*   counts  = (int*)  carve((size_t)N * 4);
    int*   row_ptr = (int*)  carve((size_t)(N + 1) * 4);
    int*   pos     = (int*)  carve((size_t)N * 4);
    int*   bsum    = (int*)  carve(128 * 4);
    const int nchunk = (E + CHUNK - 1) / CHUNK;
    int*   pcnt    = (int*)  carve((size_t)nchunk * 8 * 4);
    int*   poff    = (int*)  carve((size_t)nchunk * 8 * 4);
    u64*   stg     = (u64*)  carve((size_t)E * 8);                      // 12.8 MB
    u64*   erec    = (u64*)  carve((size_t)E * 8);                      // 12.8 MB

    float* out = (float*)d_out;

    const int nb = (N + 1023) / 1024;
    const int layer_blocks = (N + 127) / 128;

    // ---- one-time prep (independent of edges) ----
    convert_x<<<(N * 32 + 255) / 256, 256, 0, stream>>>(x, XH0, N);
    pack_W<<<16, 256, 0, stream>>>(Wr0, Ws0, Wp0);
    pack_W<<<16, 256, 0, stream>>>(Wr1, Ws1, Wp1);

    // ---- CSR build: fused histogram+partition count, scans, 2-phase reorder ----
    hipMemsetAsync(counts, 0, (size_t)N * 4, stream);
    part_count<<<nchunk, 256, 0, stream>>>(dst, E, Q, pcnt, counts);
    scan_block_sums<<<nb, 256, 0, stream>>>(counts, bsum, N);
    scan_offsets<<<1, 128, 0, stream>>>(bsum, nb, row_ptr, N);
    scan_final<<<nb, 256, 0, stream>>>(counts, bsum, row_ptr, pos, N);
    part_scan<<<1, 512, 0, stream>>>(pcnt, nchunk, row_ptr, N, Q, poff);
    part_write<<<nchunk, 256, 0, stream>>>(src, dst, ew, poff, stg, E, Q);
    part_scatter<<<768, 256, 0, stream>>>(stg, row_ptr, N, Q, pos, erec);

    // ---- Layer 0 (weighted) : XH0 -> XH1 (bf16) ----
    fused_layer<true, true><<<layer_blocks, 256, 0, stream>>>(
        XH0, row_ptr, erec, Wp0, br0, XH1, nullptr, N);

    // ---- Layer 1 (unweighted) : XH1 -> out (fp32) ----
    fused_layer<false, false><<<layer_blocks, 256, 0, stream>>>(
        XH1, row_ptr, erec, Wp1, br1, nullptr, out, N);
}

// Round 9
// 376.972 us; speedup vs baseline: 1.8219x; 1.8219x over previous
//
#include <hip/hip_runtime.h>
#include <hip/hip_bf16.h>

#ifndef D_FEAT
#define D_FEAT 128
#endif

typedef __attribute__((ext_vector_type(8))) short bf16x8;
typedef __attribute__((ext_vector_type(4))) float f32x4;
typedef unsigned long long u64;

// ---------------- bf16 helpers (RN-even) ----------------
__device__ __forceinline__ unsigned short f2bf(float f) {
    union { float f; unsigned u; } v; v.f = f;
    unsigned r = v.u + 0x7FFF + ((v.u >> 16) & 1);
    return (unsigned short)(r >> 16);
}
__device__ __forceinline__ float bf2f_lo(unsigned u) {
    union { unsigned u; float f; } v; v.u = u << 16; return v.f;
}
__device__ __forceinline__ float bf2f_hi(unsigned u) {
    union { unsigned u; float f; } v; v.u = u & 0xFFFF0000u; return v.f;
}
__device__ __forceinline__ float bfu(unsigned short s) {
    union { unsigned u; float f; } v; v.u = ((unsigned)s) << 16; return v.f;
}

// ---------------------------------------------------------------------------
// Scan kernels for per-node CSR offsets (row_ptr, pos insert cursors).
// ---------------------------------------------------------------------------
__global__ void scan_block_sums(const int* __restrict__ counts, int* __restrict__ bsum, int N) {
    __shared__ int red[256];
    const int b = blockIdx.x, t = threadIdx.x;
    const int base = b * 1024 + t * 4;
    int s = 0;
#pragma unroll
    for (int j = 0; j < 4; ++j) { int i = base + j; if (i < N) s += counts[i]; }
    red[t] = s; __syncthreads();
    for (int off = 128; off > 0; off >>= 1) {
        if (t < off) red[t] += red[t + off];
        __syncthreads();
    }
    if (t == 0) bsum[b] = red[0];
}

__global__ void scan_offsets(int* __restrict__ bsum, int nb, int* __restrict__ row_ptr, int N) {
    __shared__ int sh[128];
    const int t = threadIdx.x;
    const int v = (t < nb) ? bsum[t] : 0;
    sh[t] = v; __syncthreads();
    for (int off = 1; off < 128; off <<= 1) {
        int add = (t >= off) ? sh[t - off] : 0;
        __syncthreads();
        sh[t] += add;
        __syncthreads();
    }
    const int incl = sh[t];
    if (t < nb) bsum[t] = incl - v;
    if (t == nb - 1) row_ptr[N] = incl;
}

__global__ void scan_final(const int* __restrict__ counts, const int* __restrict__ bsum,
                           int* __restrict__ row_ptr, int* __restrict__ pos, int N) {
    __shared__ int tsum[256];
    const int b = blockIdx.x, t = threadIdx.x;
    const int base = b * 1024 + t * 4;
    int c[4]; int s = 0;
#pragma unroll
    for (int j = 0; j < 4; ++j) { int i = base + j; c[j] = (i < N) ? counts[i] : 0; s += c[j]; }
    tsum[t] = s; __syncthreads();
    const int v = s;
    for (int off = 1; off < 256; off <<= 1) {
        int add = (t >= off) ? tsum[t - off] : 0;
        __syncthreads();
        tsum[t] += add;
        __syncthreads();
    }
    int excl = tsum[t] - v + bsum[b];
#pragma unroll
    for (int j = 0; j < 4; ++j) {
        int i = base + j;
        if (i < N) { row_ptr[i] = excl; pos[i] = excl; excl += c[j]; }
    }
}

// ---------------------------------------------------------------------------
// Single-pass edge split: per-block LDS partition counts + per-node histogram,
// slack-reserved global regions (8 cursor atomics/block), packed 8B records.
// Record: src | dst<<20 | bf16(w)<<40  (N < 2^20).
// ---------------------------------------------------------------------------
#define CHUNK 2048

__global__ void init_pcur(int* __restrict__ pcur, int cap) {
    if (threadIdx.x < 8) pcur[threadIdx.x] = threadIdx.x * cap;
}

__global__ void split_edges(const int* __restrict__ src, const int* __restrict__ dst,
                            const float* __restrict__ ew,
                            int E, int Q,
                            int* __restrict__ pcur,     // 8 cursors, init p*cap
                            int* __restrict__ counts,   // per-node histogram
                            u64* __restrict__ stg) {
    __shared__ int cnt[8], base[8];
    const int t = threadIdx.x;
    if (t < 8) cnt[t] = 0;
    __syncthreads();
    const int lo = blockIdx.x * CHUNK;
    const int hi = min(lo + CHUNK, E);
    for (int i = lo + t; i < hi; i += 256) {
        const int d = dst[i];
        atomicAdd(&cnt[d / Q], 1);
        atomicAdd(&counts[d], 1);
    }
    __syncthreads();
    if (t < 8) base[t] = atomicAdd(&pcur[t], cnt[t]);
    __syncthreads();
    if (t < 8) cnt[t] = 0;
    __syncthreads();
    for (int i = lo + t; i < hi; i += 256) {
        const int d = dst[i];
        const int p = d / Q;
        const int off = atomicAdd(&cnt[p], 1);
        stg[base[p] + off] = (u64)(unsigned)src[i] | ((u64)(unsigned)d << 20)
                           | ((u64)f2bf(ew[i]) << 40);
    }
}

// Blocks pinned to partition via bid&7: scattered writes confined to the
// partition's ~1.6MB erec region + 50KB pos -> L2-resident.
__global__ void part_scatter(const u64* __restrict__ stg,
                             const int* __restrict__ pcur, int cap,
                             int* __restrict__ pos, u64* __restrict__ erec) {
    const int p = blockIdx.x & 7;
    const int sub = blockIdx.x >> 3;
    const int nsub = gridDim.x >> 3;
    const int beg = p * cap;
    const int end = pcur[p];
    for (int i = beg + sub * 256 + threadIdx.x; i < end; i += nsub * 256) {
        const u64 rec = stg[i];
        const int d = (int)((rec >> 20) & 0xFFFFF);
        const int fp = atomicAdd(&pos[d], 1);
        erec[fp] = rec;
    }
}

// ---------------------------------------------------------------------------
// x fp32 -> bf16 into AX[:,128:256]
// ---------------------------------------------------------------------------
__global__ void convert_x(const float* __restrict__ x,
                          unsigned short* __restrict__ AX, int N) {
    int i = blockIdx.x * blockDim.x + threadIdx.x;
    if (i >= N * 32) return;
    const int row = i >> 5;
    const int c4 = (i & 31) * 4;
    float4 v = *reinterpret_cast<const float4*>(x + (size_t)row * 128 + c4);
    unsigned lo = (unsigned)f2bf(v.x) | ((unsigned)f2bf(v.y) << 16);
    unsigned hi = (unsigned)f2bf(v.z) | ((unsigned)f2bf(v.w) << 16);
    *reinterpret_cast<uint2*>(AX + (size_t)row * 256 + 128 + c4) = make_uint2(lo, hi);
}

// ---------------------------------------------------------------------------
// Pack W = [Wr;Ws] (256x128 fp32) into canonical B-fragment order, bf16:
// Wp[((ks*8 + ct)*64 + lane)*8 + j] = W[ks*32 + (lane>>4)*8 + j][ct*16 + (lane&15)]
// ---------------------------------------------------------------------------
__global__ void pack_W(const float* __restrict__ Wr, const float* __restrict__ Ws,
                       unsigned short* __restrict__ Wp) {
    int t = blockIdx.x * blockDim.x + threadIdx.x;   // 0..4095
    if (t >= 4096) return;
    const int lane = t & 63;
    const int ct = (t >> 6) & 7;
    const int ks = t >> 9;
    const int col = ct * 16 + (lane & 15);
    const int kbase = ks * 32 + (lane >> 4) * 8;
    unsigned short v[8];
#pragma unroll
    for (int j = 0; j < 8; ++j) {
        const int k = kbase + j;
        const float w = (k < 128) ? Wr[(size_t)k * 128 + col]
                                  : Ws[(size_t)(k - 128) * 128 + col];
        v[j] = f2bf(w);
    }
    *reinterpret_cast<uint4*>(Wp + (size_t)t * 8) = *reinterpret_cast<uint4*>(v);
}

// ---------------------------------------------------------------------------
// Gather-aggregate v2: one wave per node; 4 edges processed per load instr
// (lane group g=lane>>4 handles edge i+g; 16 lanes x 16B = full 256B row).
// Cross-lane reduce (xor 16,32) at the end; lanes 0-15 write the row.
// Reads AX[:,128:256], writes AX[:,0:128].
// ---------------------------------------------------------------------------
template <bool WEIGHTED>
__global__ void __launch_bounds__(256)
gather_aggregate(const unsigned short* __restrict__ AX,
                 const int* __restrict__ row_ptr,
                 const u64* __restrict__ erec,
                 unsigned short* __restrict__ AXagg,
                 int N) {
    const int node = blockIdx.x * 4 + (threadIdx.x >> 6);
    const int lane = threadIdx.x & 63;
    if (node >= N) return;
    const int g = lane >> 4;      // edge subgroup 0..3
    const int c = lane & 15;      // 16B column -> feats c*8..c*8+7

    const int beg = row_ptr[node];
    const int end = row_ptr[node + 1];

    float acc[8];
#pragma unroll
    for (int j = 0; j < 8; ++j) acc[j] = 0.f;

    auto body = [&](int i) {
        const u64 r = erec[i];
        const float w = WEIGHTED ? bfu((unsigned short)(r >> 40)) : 1.f;
        const uint4 v = *reinterpret_cast<const uint4*>(
            AX + (size_t)(r & 0xFFFFF) * 256 + 128 + c * 8);
        acc[0] += w * bf2f_lo(v.x); acc[1] += w * bf2f_hi(v.x);
        acc[2] += w * bf2f_lo(v.y); acc[3] += w * bf2f_hi(v.y);
        acc[4] += w * bf2f_lo(v.z); acc[5] += w * bf2f_hi(v.z);
        acc[6] += w * bf2f_lo(v.w); acc[7] += w * bf2f_hi(v.w);
    };

    int i = beg + g;
    for (; i + 4 < end; i += 8) { body(i); body(i + 4); }
    if (i < end) body(i);

    // reduce across the 4 edge subgroups
#pragma unroll
    for (int j = 0; j < 8; ++j) {
        acc[j] += __shfl_xor(acc[j], 16);
        acc[j] += __shfl_xor(acc[j], 32);
    }

    if (lane < 16) {
        uint4 o;
        o.x = (unsigned)f2bf(acc[0]) | ((unsigned)f2bf(acc[1]) << 16);
        o.y = (unsigned)f2bf(acc[2]) | ((unsigned)f2bf(acc[3]) << 16);
        o.z = (unsigned)f2bf(acc[4]) | ((unsigned)f2bf(acc[5]) << 16);
        o.w = (unsigned)f2bf(acc[6]) | ((unsigned)f2bf(acc[7]) << 16);
        *reinterpret_cast<uint4*>(AXagg + (size_t)node * 256 + c * 8) = o;
    }
}

// ---------------------------------------------------------------------------
// MFMA GEMM: out = relu(AX @ [Wr;Ws] + br), K=256, bf16 in, fp32 acc.
// Wave = 32 rows x 128 cols (2x8 fragments of 16x16x32). A direct from global.
// ---------------------------------------------------------------------------
template <bool TO_BF16>
__global__ void __launch_bounds__(256)
gemm_mfma(const unsigned short* __restrict__ AX,
          const unsigned short* __restrict__ Wp,
          const float* __restrict__ br,
          float* __restrict__ out,
          unsigned short* __restrict__ AXh,
          int N) {
    const int tid = threadIdx.x;
    const int wave = tid >> 6;
    const int lane = tid & 63;
    const int r0 = blockIdx.x * 128 + wave * 32;
    const int lk = (lane >> 4) * 8;

    int ra = r0 + (lane & 15);
    int rb = ra + 16;
    if (ra >= N) ra = N - 1;   // clamped loads; stores guarded below
    if (rb >= N) rb = N - 1;
    const unsigned short* pa = AX + (size_t)ra * 256 + lk;
    const unsigned short* pb = AX + (size_t)rb * 256 + lk;
    const unsigned short* pw = Wp + (size_t)lane * 8;

    f32x4 acc[2][8];
#pragma unroll
    for (int rt = 0; rt < 2; ++rt)
#pragma unroll
        for (int ct = 0; ct < 8; ++ct)
            acc[rt][ct] = (f32x4){0.f, 0.f, 0.f, 0.f};

#pragma unroll
    for (int ks = 0; ks < 8; ++ks) {
        const bf16x8 a0 = *reinterpret_cast<const bf16x8*>(pa + ks * 32);
        const bf16x8 a1 = *reinterpret_cast<const bf16x8*>(pb + ks * 32);
#pragma unroll
        for (int ct = 0; ct < 8; ++ct) {
            const bf16x8 b = *reinterpret_cast<const bf16x8*>(pw + (((ks << 3) + ct) << 9));
            acc[0][ct] = __builtin_amdgcn_mfma_f32_16x16x32_bf16(a0, b, acc[0][ct], 0, 0, 0);
            acc[1][ct] = __builtin_amdgcn_mfma_f32_16x16x32_bf16(a1, b, acc[1][ct], 0, 0, 0);
        }
    }

    const int crow = (lane >> 4) * 4;
    const int ccol = lane & 15;
#pragma unroll
    for (int ct = 0; ct < 8; ++ct) {
        const int col = ct * 16 + ccol;
        const float bias = br[col];
#pragma unroll
        for (int rt = 0; rt < 2; ++rt) {
#pragma unroll
            for (int reg = 0; reg < 4; ++reg) {
                const int row = r0 + rt * 16 + crow + reg;
                if (row >= N) continue;
                const float v = fmaxf(acc[rt][ct][reg] + bias, 0.f);
                if (TO_BF16) {
                    AXh[(size_t)row * 256 + 128 + col] = f2bf(v);
                } else {
                    out[(size_t)row * 128 + col] = v;
                }
            }
        }
    }
}

extern "C" void kernel_launch(void* const* d_in, const int* in_sizes, int n_in,
                              void* d_out, int out_size, void* d_ws, size_t ws_size,
                              hipStream_t stream) {
    const float* x  = (const float*)d_in[0];
    const int*   ei = (const int*)d_in[1];     // [2, E] int32 (JAX x64 disabled)
    const float* ew = (const float*)d_in[2];
    const float* Wr0 = (const float*)d_in[3];
    const float* br0 = (const float*)d_in[4];
    const float* Ws0 = (const float*)d_in[5];
    const float* Wr1 = (const float*)d_in[6];
    const float* br1 = (const float*)d_in[7];
    const float* Ws1 = (const float*)d_in[8];

    const int N = in_sizes[0] / D_FEAT;
    const int E = in_sizes[1] / 2;
    const int* src = ei;
    const int* dst = ei + E;
    const int Q = (N + 7) / 8;              // dst-partition width
    const int cap = E / 8 + 65536;          // slack-reserved partition capacity

    // ---- workspace carve-up (16B aligned), ~83 MB ----
    char* w = (char*)d_ws;
    auto carve = [&](size_t bytes) { char* p = w; w += (bytes + 15) & ~(size_t)15; return p; };
    unsigned short* AX  = (unsigned short*)carve((size_t)N * 256 * 2);  // 51.2 MB
    unsigned short* Wp0 = (unsigned short*)carve(256 * 128 * 2);
    unsigned short* Wp1 = (unsigned short*)carve(256 * 128 * 2);
    int*   counts  = (int*)  carve((size_t)N * 4);
    int*   row_ptr = (int*)  carve((size_t)(N + 1) * 4);
    int*   pos     = (int*)  carve((size_t)N * 4);
    int*   bsum    = (int*)  carve(128 * 4);
    int*   pcur    = (int*)  carve(8 * 4);
    u64*   stg     = (u64*)  carve((size_t)cap * 8 * 8);                // 17 MB
    u64*   erec    = (u64*)  carve((size_t)E * 8);                      // 12.8 MB

    float* out = (float*)d_out;

    const int nb = (N + 1023) / 1024;
    const int nchunk = (E + CHUNK - 1) / CHUNK;
    const int gather_blocks = (N + 3) / 4;
    const int gemm_blocks = (N + 127) / 128;

    // ---- one-time prep (independent of edges) ----
    convert_x<<<(N * 32 + 255) / 256, 256, 0, stream>>>(x, AX, N);
    pack_W<<<16, 256, 0, stream>>>(Wr0, Ws0, Wp0);
    pack_W<<<16, 256, 0, stream>>>(Wr1, Ws1, Wp1);

    // ---- edge pipeline: split -> scans -> partition-local scatter ----
    hipMemsetAsync(counts, 0, (size_t)N * 4, stream);
    init_pcur<<<1, 64, 0, stream>>>(pcur, cap);
    split_edges<<<nchunk, 256, 0, stream>>>(src, dst, ew, E, Q, pcur, counts, stg);
    scan_block_sums<<<nb, 256, 0, stream>>>(counts, bsum, N);
    scan_offsets<<<1, 128, 0, stream>>>(bsum, nb, row_ptr, N);
    scan_final<<<nb, 256, 0, stream>>>(counts, bsum, row_ptr, pos, N);
    part_scatter<<<768, 256, 0, stream>>>(stg, pcur, cap, pos, erec);

    // ---- Layer 0 (weighted) ----
    gather_aggregate<true><<<gather_blocks, 256, 0, stream>>>(AX, row_ptr, erec, AX, N);
    gemm_mfma<true><<<gemm_blocks, 256, 0, stream>>>(AX, Wp0, br0, nullptr, AX, N);

    // ---- Layer 1 (unweighted — reference omits edge_weight here) ----
    gather_aggregate<false><<<gather_blocks, 256, 0, stream>>>(AX, row_ptr, erec, AX, N);
    gemm_mfma<false><<<gemm_blocks, 256, 0, stream>>>(AX, Wp1, br1, out, nullptr, N);
}

// Round 10
// 370.100 us; speedup vs baseline: 1.8557x; 1.0186x over previous
//
#include <hip/hip_runtime.h>
#include <hip/hip_bf16.h>

#ifndef D_FEAT
#define D_FEAT 128
#endif

typedef __attribute__((ext_vector_type(8))) short bf16x8;
typedef __attribute__((ext_vector_type(4))) float f32x4;
typedef unsigned long long u64;

// ---------------- bf16 helpers (RN-even) ----------------
__device__ __forceinline__ unsigned short f2bf(float f) {
    union { float f; unsigned u; } v; v.f = f;
    unsigned r = v.u + 0x7FFF + ((v.u >> 16) & 1);
    return (unsigned short)(r >> 16);
}
__device__ __forceinline__ float bf2f_lo(unsigned u) {
    union { unsigned u; float f; } v; v.u = u << 16; return v.f;
}
__device__ __forceinline__ float bf2f_hi(unsigned u) {
    union { unsigned u; float f; } v; v.u = u & 0xFFFF0000u; return v.f;
}
__device__ __forceinline__ float bfu(unsigned short s) {
    union { unsigned u; float f; } v; v.u = ((unsigned)s) << 16; return v.f;
}

// ---------------------------------------------------------------------------
// Per-node in-degree histogram (grid-stride, plain device atomics).
// ---------------------------------------------------------------------------
__global__ void histogram_kernel(const int* __restrict__ dst, int* __restrict__ counts, int E) {
    for (int i = blockIdx.x * blockDim.x + threadIdx.x; i < E;
         i += gridDim.x * blockDim.x)
        atomicAdd(&counts[dst[i]], 1);
}

// ---------------------------------------------------------------------------
// Scan kernels for per-node CSR offsets (row_ptr, pos insert cursors).
// ---------------------------------------------------------------------------
__global__ void scan_block_sums(const int* __restrict__ counts, int* __restrict__ bsum, int N) {
    __shared__ int red[256];
    const int b = blockIdx.x, t = threadIdx.x;
    const int base = b * 1024 + t * 4;
    int s = 0;
#pragma unroll
    for (int j = 0; j < 4; ++j) { int i = base + j; if (i < N) s += counts[i]; }
    red[t] = s; __syncthreads();
    for (int off = 128; off > 0; off >>= 1) {
        if (t < off) red[t] += red[t + off];
        __syncthreads();
    }
    if (t == 0) bsum[b] = red[0];
}

__global__ void scan_offsets(int* __restrict__ bsum, int nb, int* __restrict__ row_ptr, int N) {
    __shared__ int sh[128];
    const int t = threadIdx.x;
    const int v = (t < nb) ? bsum[t] : 0;
    sh[t] = v; __syncthreads();
    for (int off = 1; off < 128; off <<= 1) {
        int add = (t >= off) ? sh[t - off] : 0;
        __syncthreads();
        sh[t] += add;
        __syncthreads();
    }
    const int incl = sh[t];
    if (t < nb) bsum[t] = incl - v;
    if (t == nb - 1) row_ptr[N] = incl;
}

__global__ void scan_final(const int* __restrict__ counts, const int* __restrict__ bsum,
                           int* __restrict__ row_ptr, int* __restrict__ pos, int N) {
    __shared__ int tsum[256];
    const int b = blockIdx.x, t = threadIdx.x;
    const int base = b * 1024 + t * 4;
    int c[4]; int s = 0;
#pragma unroll
    for (int j = 0; j < 4; ++j) { int i = base + j; c[j] = (i < N) ? counts[i] : 0; s += c[j]; }
    tsum[t] = s; __syncthreads();
    const int v = s;
    for (int off = 1; off < 256; off <<= 1) {
        int add = (t >= off) ? tsum[t - off] : 0;
        __syncthreads();
        tsum[t] += add;
        __syncthreads();
    }
    int excl = tsum[t] - v + bsum[b];
#pragma unroll
    for (int j = 0; j < 4; ++j) {
        int i = base + j;
        if (i < N) { row_ptr[i] = excl; pos[i] = excl; excl += c[j]; }
    }
}

// ---------------------------------------------------------------------------
// Direct partition-pinned scatter: partition p = bid&7 (maps to one XCD by
// dispatch round-robin). Each partition's blocks re-scan the full edge list
// (streaming reads, L2/L3-served) and scatter only their dst-range: random
// writes confined to the partition's ~1.6MB erec window + 50KB pos cursors.
// Record: src | dst<<20 | bf16(w)<<40  (N < 2^20).
// ---------------------------------------------------------------------------
__global__ void scatter_direct(const int* __restrict__ src, const int* __restrict__ dst,
                               const float* __restrict__ ew, int E, int Q, int N,
                               int* __restrict__ pos, u64* __restrict__ erec) {
    const int p = blockIdx.x & 7;
    const int sub = blockIdx.x >> 3;
    const int nsub = gridDim.x >> 3;
    const int lo = p * Q;
    const int hi = min(lo + Q, N);
    for (int i = sub * 256 + threadIdx.x; i < E; i += nsub * 256) {
        const int d = dst[i];
        if (d >= lo && d < hi) {
            const int fp = atomicAdd(&pos[d], 1);
            erec[fp] = (u64)(unsigned)src[i] | ((u64)(unsigned)d << 20)
                     | ((u64)f2bf(ew[i]) << 40);
        }
    }
}

// ---------------------------------------------------------------------------
// x fp32 -> bf16 into AX[:,128:256]
// ---------------------------------------------------------------------------
__global__ void convert_x(const float* __restrict__ x,
                          unsigned short* __restrict__ AX, int N) {
    int i = blockIdx.x * blockDim.x + threadIdx.x;
    if (i >= N * 32) return;
    const int row = i >> 5;
    const int c4 = (i & 31) * 4;
    float4 v = *reinterpret_cast<const float4*>(x + (size_t)row * 128 + c4);
    unsigned lo = (unsigned)f2bf(v.x) | ((unsigned)f2bf(v.y) << 16);
    unsigned hi = (unsigned)f2bf(v.z) | ((unsigned)f2bf(v.w) << 16);
    *reinterpret_cast<uint2*>(AX + (size_t)row * 256 + 128 + c4) = make_uint2(lo, hi);
}

// ---------------------------------------------------------------------------
// Pack W = [Wr;Ws] (256x128 fp32) into canonical B-fragment order, bf16:
// Wp[((ks*8 + ct)*64 + lane)*8 + j] = W[ks*32 + (lane>>4)*8 + j][ct*16 + (lane&15)]
// ---------------------------------------------------------------------------
__global__ void pack_W(const float* __restrict__ Wr, const float* __restrict__ Ws,
                       unsigned short* __restrict__ Wp) {
    int t = blockIdx.x * blockDim.x + threadIdx.x;   // 0..4095
    if (t >= 4096) return;
    const int lane = t & 63;
    const int ct = (t >> 6) & 7;
    const int ks = t >> 9;
    const int col = ct * 16 + (lane & 15);
    const int kbase = ks * 32 + (lane >> 4) * 8;
    unsigned short v[8];
#pragma unroll
    for (int j = 0; j < 8; ++j) {
        const int k = kbase + j;
        const float w = (k < 128) ? Wr[(size_t)k * 128 + col]
                                  : Ws[(size_t)(k - 128) * 128 + col];
        v[j] = f2bf(w);
    }
    *reinterpret_cast<uint4*>(Wp + (size_t)t * 8) = *reinterpret_cast<uint4*>(v);
}

// ---------------------------------------------------------------------------
// Gather-aggregate v3: one wave per node; lane group g=lane>>4 handles edge
// i+g (16 lanes x 16B = full 256B row); 4-deep unrolled (16 edges in flight).
// Cross-lane reduce (xor 16,32); lanes 0-15 write the agg row.
// Reads AX[:,128:256], writes AX[:,0:128].
// ---------------------------------------------------------------------------
template <bool WEIGHTED>
__global__ void __launch_bounds__(256)
gather_aggregate(const unsigned short* __restrict__ AX,
                 const int* __restrict__ row_ptr,
                 const u64* __restrict__ erec,
                 unsigned short* __restrict__ AXagg,
                 int N) {
    const int node = blockIdx.x * 4 + (threadIdx.x >> 6);
    const int lane = threadIdx.x & 63;
    if (node >= N) return;
    const int g = lane >> 4;      // edge subgroup 0..3
    const int c = lane & 15;      // 16B column -> feats c*8..c*8+7

    const int beg = row_ptr[node];
    const int end = row_ptr[node + 1];

    float acc[8];
#pragma unroll
    for (int j = 0; j < 8; ++j) acc[j] = 0.f;

    auto body = [&](int i) {
        const u64 r = erec[i];
        const float w = WEIGHTED ? bfu((unsigned short)(r >> 40)) : 1.f;
        const uint4 v = *reinterpret_cast<const uint4*>(
            AX + (size_t)(r & 0xFFFFF) * 256 + 128 + c * 8);
        acc[0] += w * bf2f_lo(v.x); acc[1] += w * bf2f_hi(v.x);
        acc[2] += w * bf2f_lo(v.y); acc[3] += w * bf2f_hi(v.y);
        acc[4] += w * bf2f_lo(v.z); acc[5] += w * bf2f_hi(v.z);
        acc[6] += w * bf2f_lo(v.w); acc[7] += w * bf2f_hi(v.w);
    };

    int i = beg + g;
    for (; i + 12 < end; i += 16) { body(i); body(i + 4); body(i + 8); body(i + 12); }
    for (; i < end; i += 4) body(i);

    // reduce across the 4 edge subgroups
#pragma unroll
    for (int j = 0; j < 8; ++j) {
        acc[j] += __shfl_xor(acc[j], 16);
        acc[j] += __shfl_xor(acc[j], 32);
    }

    if (lane < 16) {
        uint4 o;
        o.x = (unsigned)f2bf(acc[0]) | ((unsigned)f2bf(acc[1]) << 16);
        o.y = (unsigned)f2bf(acc[2]) | ((unsigned)f2bf(acc[3]) << 16);
        o.z = (unsigned)f2bf(acc[4]) | ((unsigned)f2bf(acc[5]) << 16);
        o.w = (unsigned)f2bf(acc[6]) | ((unsigned)f2bf(acc[7]) << 16);
        *reinterpret_cast<uint4*>(AXagg + (size_t)node * 256 + c * 8) = o;
    }
}

// ---------------------------------------------------------------------------
// MFMA GEMM: out = relu(AX @ [Wr;Ws] + br), K=256, bf16 in, fp32 acc.
// Wave = 32 rows x 128 cols (2x8 fragments of 16x16x32). A direct from global.
// ---------------------------------------------------------------------------
template <bool TO_BF16>
__global__ void __launch_bounds__(256)
gemm_mfma(const unsigned short* __restrict__ AX,
          const unsigned short* __restrict__ Wp,
          const float* __restrict__ br,
          float* __restrict__ out,
          unsigned short* __restrict__ AXh,
          int N) {
    const int tid = threadIdx.x;
    const int wave = tid >> 6;
    const int lane = tid & 63;
    const int r0 = blockIdx.x * 128 + wave * 32;
    const int lk = (lane >> 4) * 8;

    int ra = r0 + (lane & 15);
    int rb = ra + 16;
    if (ra >= N) ra = N - 1;   // clamped loads; stores guarded below
    if (rb >= N) rb = N - 1;
    const unsigned short* pa = AX + (size_t)ra * 256 + lk;
    const unsigned short* pb = AX + (size_t)rb * 256 + lk;
    const unsigned short* pw = Wp + (size_t)lane * 8;

    f32x4 acc[2][8];
#pragma unroll
    for (int rt = 0; rt < 2; ++rt)
#pragma unroll
        for (int ct = 0; ct < 8; ++ct)
            acc[rt][ct] = (f32x4){0.f, 0.f, 0.f, 0.f};

#pragma unroll
    for (int ks = 0; ks < 8; ++ks) {
        const bf16x8 a0 = *reinterpret_cast<const bf16x8*>(pa + ks * 32);
        const bf16x8 a1 = *reinterpret_cast<const bf16x8*>(pb + ks * 32);
#pragma unroll
        for (int ct = 0; ct < 8; ++ct) {
            const bf16x8 b = *reinterpret_cast<const bf16x8*>(pw + (((ks << 3) + ct) << 9));
            acc[0][ct] = __builtin_amdgcn_mfma_f32_16x16x32_bf16(a0, b, acc[0][ct], 0, 0, 0);
            acc[1][ct] = __builtin_amdgcn_mfma_f32_16x16x32_bf16(a1, b, acc[1][ct], 0, 0, 0);
        }
    }

    const int crow = (lane >> 4) * 4;
    const int ccol = lane & 15;
#pragma unroll
    for (int ct = 0; ct < 8; ++ct) {
        const int col = ct * 16 + ccol;
        const float bias = br[col];
#pragma unroll
        for (int rt = 0; rt < 2; ++rt) {
#pragma unroll
            for (int reg = 0; reg < 4; ++reg) {
                const int row = r0 + rt * 16 + crow + reg;
                if (row >= N) continue;
                const float v = fmaxf(acc[rt][ct][reg] + bias, 0.f);
                if (TO_BF16) {
                    AXh[(size_t)row * 256 + 128 + col] = f2bf(v);
                } else {
                    out[(size_t)row * 128 + col] = v;
                }
            }
        }
    }
}

extern "C" void kernel_launch(void* const* d_in, const int* in_sizes, int n_in,
                              void* d_out, int out_size, void* d_ws, size_t ws_size,
                              hipStream_t stream) {
    const float* x  = (const float*)d_in[0];
    const int*   ei = (const int*)d_in[1];     // [2, E] int32 (JAX x64 disabled)
    const float* ew = (const float*)d_in[2];
    const float* Wr0 = (const float*)d_in[3];
    const float* br0 = (const float*)d_in[4];
    const float* Ws0 = (const float*)d_in[5];
    const float* Wr1 = (const float*)d_in[6];
    const float* br1 = (const float*)d_in[7];
    const float* Ws1 = (const float*)d_in[8];

    const int N = in_sizes[0] / D_FEAT;
    const int E = in_sizes[1] / 2;
    const int* src = ei;
    const int* dst = ei + E;
    const int Q = (N + 7) / 8;              // dst-partition width

    // ---- workspace carve-up (16B aligned), ~66 MB ----
    char* w = (char*)d_ws;
    auto carve = [&](size_t bytes) { char* p = w; w += (bytes + 15) & ~(size_t)15; return p; };
    unsigned short* AX  = (unsigned short*)carve((size_t)N * 256 * 2);  // 51.2 MB
    unsigned short* Wp0 = (unsigned short*)carve(256 * 128 * 2);
    unsigned short* Wp1 = (unsigned short*)carve(256 * 128 * 2);
    int*   counts  = (int*)  carve((size_t)N * 4);
    int*   row_ptr = (int*)  carve((size_t)(N + 1) * 4);
    int*   pos     = (int*)  carve((size_t)N * 4);
    int*   bsum    = (int*)  carve(128 * 4);
    u64*   erec    = (u64*)  carve((size_t)E * 8);                      // 12.8 MB

    float* out = (float*)d_out;

    const int nb = (N + 1023) / 1024;
    const int gather_blocks = (N + 3) / 4;
    const int gemm_blocks = (N + 127) / 128;

    // ---- one-time prep (independent of edges) ----
    convert_x<<<(N * 32 + 255) / 256, 256, 0, stream>>>(x, AX, N);
    pack_W<<<16, 256, 0, stream>>>(Wr0, Ws0, Wp0);
    pack_W<<<16, 256, 0, stream>>>(Wr1, Ws1, Wp1);

    // ---- CSR build: histogram -> scans -> direct partition-pinned scatter ----
    hipMemsetAsync(counts, 0, (size_t)N * 4, stream);
    histogram_kernel<<<2048, 256, 0, stream>>>(dst, counts, E);
    scan_block_sums<<<nb, 256, 0, stream>>>(counts, bsum, N);
    scan_offsets<<<1, 128, 0, stream>>>(bsum, nb, row_ptr, N);
    scan_final<<<nb, 256, 0, stream>>>(counts, bsum, row_ptr, pos, N);
    scatter_direct<<<2048, 256, 0, stream>>>(src, dst, ew, E, Q, N, pos, erec);

    // ---- Layer 0 (weighted) ----
    gather_aggregate<true><<<gather_blocks, 256, 0, stream>>>(AX, row_ptr, erec, AX, N);
    gemm_mfma<true><<<gemm_blocks, 256, 0, stream>>>(AX, Wp0, br0, nullptr, AX, N);

    // ---- Layer 1 (unweighted — reference omits edge_weight here) ----
    gather_aggregate<false><<<gather_blocks, 256, 0, stream>>>(AX, row_ptr, erec, AX, N);
    gemm_mfma<false><<<gemm_blocks, 256, 0, stream>>>(AX, Wp1, br1, out, nullptr, N);
}